// Round 5
// baseline (279.380 us; speedup 1.0000x reference)
//
#include <hip/hip_runtime.h>

#define B_  32
#define T_  256
#define F_  64
#define C_  16
#define CO_ 16
#define P_  64
#define S_  32
#define K_  4
#define FC_ 1024   // F*C
#define OUTC 96
#define TT  8      // t-tile per block
#define NS  14     // TT + 6 halo slices (dilation*(K-1) = 6)

// Native clang vector type: __builtin_nontemporal_store accepts this,
// unlike HIP's float4 wrapper class. Identical 16B layout.
typedef float floatx4 __attribute__((ext_vector_type(4)));

// Workgroup barrier that drains ONLY LDS (lgkmcnt), not global stores (vmcnt).
// __syncthreads() forces s_waitcnt vmcnt(0) before s_barrier, which makes every
// wave wait for the previous 12KB output dump to reach L2. The per-tl barriers
// in phase 2 only protect LDS staging reuse -> lgkmcnt(0) suffices; global
// stores can stay in flight across the barrier (output is never re-read).
#define BARRIER_LGKM() asm volatile("s_waitcnt lgkmcnt(0)\n\ts_barrier" ::: "memory")

__global__ __launch_bounds__(512, 4) void tpc_fused(
    const float* __restrict__ x, const float* __restrict__ stat,
    const float* __restrict__ cw, const float* __restrict__ cb,
    const float* __restrict__ Wp, const float* __restrict__ bp,
    float* __restrict__ out)
{
    __shared__ __align__(16) float xs[NS * FC_];   // 57.3 KB
    __shared__ __align__(16) float u[4096];        // 16 KB multi-use

    int tid = threadIdx.x;
    int blk = blockIdx.x;      // 0..1023
    int b  = blk >> 5;
    int t0 = (blk & 31) * TT;

    // ---- stage x[t0-6 .. t0+TT-1, :, :] into LDS (zero left pad) ----
    #pragma unroll
    for (int it = 0; it < 7; ++it) {
        int v = it * 512 + tid;            // float4 id, NS*256 = 3584 total
        int slice = v >> 8;
        int pos   = v & 255;
        int tg = t0 - 6 + slice;
        float4 val = make_float4(0.f, 0.f, 0.f, 0.f);
        if (tg >= 0)
            val = *(const float4*)(x + ((size_t)(b * T_ + tg)) * FC_ + pos * 4);
        *(float4*)(xs + slice * FC_ + pos * 4) = val;
    }
    __syncthreads();

    // ---- phase 1: point GEMM partials; wave = one 128-wide k slice ----
    {
        int p  = tid & 63;
        int ks = tid >> 6;                 // 0..7
        float acc[TT];
        #pragma unroll
        for (int r = 0; r < TT; ++r) acc[r] = 0.f;
        int k0base = ks * 128;
        for (int kk = 0; kk < 128; kk += 4) {
            int k0 = k0base + kk;
            float w0 = Wp[(size_t)(k0 + 0) * P_ + p];
            float w1 = Wp[(size_t)(k0 + 1) * P_ + p];
            float w2 = Wp[(size_t)(k0 + 2) * P_ + p];
            float w3 = Wp[(size_t)(k0 + 3) * P_ + p];
            #pragma unroll
            for (int r = 0; r < TT; ++r) {
                float4 xv = *(const float4*)(xs + (6 + r) * FC_ + k0);
                acc[r] += xv.x * w0 + xv.y * w1 + xv.z * w2 + xv.w * w3;
            }
        }
        #pragma unroll
        for (int r = 0; r < TT; ++r)
            u[(ks * TT + r) * P_ + p] = acc[r];
    }
    __syncthreads();

    // ---- phase 1b: reduce + bias + static; relu into u[3072..3584) ----
    {
        int p = tid & 63;
        int r = tid >> 6;                  // row 0..7
        float s = bp[p];
        const float* wst = Wp + (size_t)FC_ * P_;
        #pragma unroll 8
        for (int si = 0; si < S_; ++si)
            s += stat[b * S_ + si] * wst[si * P_ + p];
        #pragma unroll
        for (int ks = 0; ks < 8; ++ks)
            s += u[(ks * TT + r) * P_ + p];
        __syncthreads();                   // all part reads done before overwrite
        u[3072 + r * P_ + p] = fmaxf(s, 0.f);
    }
    __syncthreads();

    // ---- phase 2: conv + concat fusion, LDS-staged full-line dumps ----
    int co = tid & 15;
    int fh = tid >> 4;                     // 0..31 (local f within half)
    int p  = tid & 63;
    int fg = tid >> 6;                     // 0..7

    #pragma unroll
    for (int half = 0; half < 2; ++half) {
        int f = half * 32 + fh;
        // conv weights for (f, co): 64 floats (cw read once per block total)
        float w[64];
        const float4* wg = (const float4*)(cw + ((size_t)(f * CO_ + co)) * (C_ * K_));
        #pragma unroll
        for (int j = 0; j < 16; ++j) {
            float4 t4 = wg[j];
            w[4 * j + 0] = t4.x; w[4 * j + 1] = t4.y;
            w[4 * j + 2] = t4.z; w[4 * j + 3] = t4.w;
        }
        float bias = cb[f * CO_ + co];

        for (int tl = 0; tl < TT; ++tl) {
            // conv result -> staging
            float temp = bias;
            #pragma unroll
            for (int k = 0; k < K_; ++k) {
                const float* sp = xs + (tl + 2 * k) * FC_ + f * C_;
                #pragma unroll
                for (int c4 = 0; c4 < 4; ++c4) {
                    float4 xv = *(const float4*)(sp + c4 * 4);
                    temp += xv.x * w[(c4 * 4 + 0) * 4 + k];
                    temp += xv.y * w[(c4 * 4 + 1) * 4 + k];
                    temp += xv.z * w[(c4 * 4 + 2) * 4 + k];
                    temp += xv.w * w[(c4 * 4 + 3) * 4 + k];
                }
            }
            u[fh * OUTC + 16 + co] = fmaxf(temp, 0.f);
            // x passthrough -> staging
            u[fh * OUTC + co] = fmaxf(xs[(tl + 6) * FC_ + f * C_ + co], 0.f);
            // point broadcast -> staging (reads u[3072..), writes u[0..3072): disjoint)
            float pvv = u[3072 + tl * P_ + p];
            #pragma unroll
            for (int fo = 0; fo < 4; ++fo)
                u[(fo * 8 + fg) * OUTC + 32 + p] = pvv;
            BARRIER_LGKM();                // LDS-only drain; no vmcnt stall
            // dump 12 KB contiguous (full 128B lines); nontemporal: the output
            // is write-once, keep it from evicting Wp/cw from L2
            {
                const floatx4* src = (const floatx4*)u;
                floatx4* dst = (floatx4*)(out + ((size_t)(b * T_ + t0 + tl)) * F_ * OUTC
                                          + half * 3072);
                __builtin_nontemporal_store(src[tid], &dst[tid]);
                if (tid < 256)
                    __builtin_nontemporal_store(src[512 + tid], &dst[512 + tid]);
            }
            BARRIER_LGKM();                // protect staging reuse; stores stay in flight
        }
    }
}

extern "C" void kernel_launch(void* const* d_in, const int* in_sizes, int n_in,
                              void* d_out, int out_size, void* d_ws, size_t ws_size,
                              hipStream_t stream) {
    const float* x    = (const float*)d_in[0];
    const float* stat = (const float*)d_in[1];
    const float* cw   = (const float*)d_in[2];
    const float* cb   = (const float*)d_in[3];
    const float* Wp   = (const float*)d_in[4];
    const float* bp   = (const float*)d_in[5];
    float* out = (float*)d_out;

    tpc_fused<<<1024, 512, 0, stream>>>(x, stat, cw, cb, Wp, bp, out);
}